// Round 6
// baseline (219.687 us; speedup 1.0000x reference)
//
#include <hip/hip_runtime.h>

#define T_SEQ 2048
#define C_DIM 1024
#define NH    16
#define NKV   4
#define HD    64
#define WIN   512

typedef __bf16 bf16x8 __attribute__((ext_vector_type(8)));
typedef __bf16 bf16x4 __attribute__((ext_vector_type(4)));
typedef float f32x4 __attribute__((ext_vector_type(4)));

#define MFMA16(a, b, c) __builtin_amdgcn_mfma_f32_16x16x32_bf16(a, b, c, 0, 0, 0)

// ---------------- prep: fused f32->bf16 casts + RoPE table ----------------
__global__ __launch_bounds__(256) void prep_kernel(const float* __restrict__ x,
                                                   const float* __restrict__ Wq,
                                                   const float* __restrict__ Wkv,
                                                   const float* __restrict__ Wp,
                                                   __bf16* __restrict__ xb,
                                                   __bf16* __restrict__ Wqkvb,
                                                   __bf16* __restrict__ Wpb,
                                                   float2* __restrict__ ropeT) {
  int b = blockIdx.x;
  if (b >= 4608) {
    int idx = (b - 4608) * 256 + threadIdx.x;  // < 65536
    int t = idx >> 5, i = idx & 31;
    float theta = exp2f(-(float)i * (13.287712379549449f / 32.0f));
    float s, c;
    sincosf((float)t * theta, &s, &c);
    ropeT[idx] = make_float2(c, s);
    return;
  }
  const float* src;
  __bf16* dst;
  int off;
  if (b < 2048)      { src = x;   dst = xb;                off = b; }
  else if (b < 3072) { src = Wq;  dst = Wqkvb;             off = b - 2048; }
  else if (b < 3584) { src = Wkv; dst = Wqkvb + (1 << 20); off = b - 3072; }
  else               { src = Wp;  dst = Wpb;               off = b - 3584; }
  int i = off * 1024 + threadIdx.x * 4;
  float4 v = *(const float4*)(src + i);
  bf16x4 o;
  o[0] = (__bf16)v.x; o[1] = (__bf16)v.y; o[2] = (__bf16)v.z; o[3] = (__bf16)v.w;
  *(bf16x4*)(dst + i) = o;
}

// ---------------- GEMM core: 128x64 tile, BK=64, depth-2 VGPR prefetch + LDS dbuf ----
// At 1.5-2 blocks/CU with poison-cold caches, every staging load is an ~900-cyc HBM miss;
// depth-1 prefetch (R4/R5) only covered ~300 cyc of MFMA. Depth-2 keeps two K-slabs in
// flight: the ds_write of slab i+1 needs only a PARTIAL vmcnt wait (slab i+2's loads stay
// outstanding), so the exposed latency per iter shrinks to ~max(0, 900 - 2*compute).
// No sched_barrier: m141 showed order-pinning can regress badly; trust the scheduler.
__device__ __forceinline__ void gemm_core(const __bf16* __restrict__ A,
                                          const __bf16* __restrict__ B,
                                          int K, int m0, int n0,
                                          __bf16* AsB, __bf16* BsB,
                                          f32x4 (&acc)[2][4]) {
  const int tid = threadIdx.x;
  const int w = tid >> 6, l = tid & 63;
  const int quad = l >> 4, r16 = l & 15;
  const int arow = tid >> 1;   // 0..127
  const int brow = tid >> 2;   // 0..63
  const __bf16* gA = A + (size_t)(m0 + arow) * K + (tid & 1) * 32;
  const __bf16* gB = B + (size_t)(n0 + brow) * K + (tid & 3) * 16;
  int wA[4], wB[2];
#pragma unroll
  for (int q = 0; q < 4; ++q) wA[q] = arow * 64 + ((((tid & 1) * 4 + q) ^ (arow & 7)) * 8);
#pragma unroll
  for (int q = 0; q < 2; ++q) wB[q] = brow * 64 + ((((tid & 3) * 2 + q) ^ (brow & 7)) * 8);
  int rA[2][2], rB[4][2];
#pragma unroll
  for (int mt = 0; mt < 2; ++mt)
#pragma unroll
    for (int ks = 0; ks < 2; ++ks) {
      int row = w * 32 + mt * 16 + r16;
      rA[mt][ks] = row * 64 + (((ks * 4 + quad) ^ (row & 7)) * 8);
    }
#pragma unroll
  for (int nt = 0; nt < 4; ++nt)
#pragma unroll
    for (int ks = 0; ks < 2; ++ks) {
      int row = nt * 16 + r16;
      rB[nt][ks] = row * 64 + (((ks * 4 + quad) ^ (row & 7)) * 8);
    }
  const int nIter = K >> 6;  // 16
  uint4 pa[2][4], pb[2][2];
#pragma unroll
  for (int s = 0; s < 2; ++s) {
    const uint4* a = (const uint4*)(gA + (s << 6));
    pa[s][0] = a[0]; pa[s][1] = a[1]; pa[s][2] = a[2]; pa[s][3] = a[3];
    const uint4* b = (const uint4*)(gB + (s << 6));
    pb[s][0] = b[0]; pb[s][1] = b[1];
  }
#pragma unroll
  for (int q = 0; q < 4; ++q) *(uint4*)(AsB + wA[q]) = pa[0][q];
#pragma unroll
  for (int q = 0; q < 2; ++q) *(uint4*)(BsB + wB[q]) = pb[0][q];
  __syncthreads();
  int cur = 0;
  for (int it = 0; it < nIter; ++it) {
    if (it + 2 < nIter) {  // prefetch slab it+2 into the reg-set freed last iter
      const int s = it & 1;
      const uint4* a = (const uint4*)(gA + ((it + 2) << 6));
      pa[s][0] = a[0]; pa[s][1] = a[1]; pa[s][2] = a[2]; pa[s][3] = a[3];
      const uint4* b = (const uint4*)(gB + ((it + 2) << 6));
      pb[s][0] = b[0]; pb[s][1] = b[1];
    }
    const __bf16* Asc = AsB + cur * 8192;
    const __bf16* Bsc = BsB + cur * 4096;
#pragma unroll
    for (int ks = 0; ks < 2; ++ks) {
      bf16x8 a0 = *(const bf16x8*)(Asc + rA[0][ks]);
      bf16x8 a1 = *(const bf16x8*)(Asc + rA[1][ks]);
      bf16x8 b0 = *(const bf16x8*)(Bsc + rB[0][ks]);
      bf16x8 b1 = *(const bf16x8*)(Bsc + rB[1][ks]);
      bf16x8 b2 = *(const bf16x8*)(Bsc + rB[2][ks]);
      bf16x8 b3 = *(const bf16x8*)(Bsc + rB[3][ks]);
      acc[0][0] = MFMA16(a0, b0, acc[0][0]);
      acc[0][1] = MFMA16(a0, b1, acc[0][1]);
      acc[0][2] = MFMA16(a0, b2, acc[0][2]);
      acc[0][3] = MFMA16(a0, b3, acc[0][3]);
      acc[1][0] = MFMA16(a1, b0, acc[1][0]);
      acc[1][1] = MFMA16(a1, b1, acc[1][1]);
      acc[1][2] = MFMA16(a1, b2, acc[1][2]);
      acc[1][3] = MFMA16(a1, b3, acc[1][3]);
    }
    if (it + 1 < nIter) {
      __bf16* Asn = AsB + (cur ^ 1) * 8192;
      __bf16* Bsn = BsB + (cur ^ 1) * 4096;
      const int s = (it + 1) & 1;
#pragma unroll
      for (int q = 0; q < 4; ++q) *(uint4*)(Asn + wA[q]) = pa[s][q];
#pragma unroll
      for (int q = 0; q < 2; ++q) *(uint4*)(Bsn + wB[q]) = pb[s][q];
      __syncthreads();
      cur ^= 1;
    }
  }
}

// ---------------- QKV GEMM with fused norm+RoPE (Q,K) and V-transpose epilogue ----------
__global__ __launch_bounds__(256) void gemm_qkv_kernel(const __bf16* __restrict__ xb,
                                                       const __bf16* __restrict__ Wqkvb,
                                                       const float2* __restrict__ ropeT,
                                                       __bf16* __restrict__ Qb,
                                                       __bf16* __restrict__ Kb,
                                                       __bf16* __restrict__ Vt) {
  __shared__ __align__(16) __bf16 As[2 * 8192];
  __shared__ __align__(16) __bf16 Bs[2 * 4096];
  f32x4 acc[2][4] = {};
  const int m0 = blockIdx.y * 128, n0 = blockIdx.x * 64;
  gemm_core(xb, Wqkvb, C_DIM, m0, n0, As, Bs, acc);
  const int tid = threadIdx.x;
  const int w = tid >> 6, l = tid & 63, quad = l >> 4, r16 = l & 15;
  if (n0 < 1280) {  // Q or K: L2-norm + RoPE
    const bool isQ = n0 < 1024;
    const int head = isQ ? (n0 >> 6) : ((n0 - 1024) >> 6);
    __bf16* dstBase = (isQ ? Qb : Kb) + (size_t)head * T_SEQ * HD;
    const float osc = isQ ? 0.125f : 1.0f;
#pragma unroll
    for (int mt = 0; mt < 2; ++mt) {
#pragma unroll
      for (int r = 0; r < 4; ++r) {
        float ss = acc[mt][0][r] * acc[mt][0][r] + acc[mt][1][r] * acc[mt][1][r] +
                   acc[mt][2][r] * acc[mt][2][r] + acc[mt][3][r] * acc[mt][3][r];
#pragma unroll
        for (int m = 1; m < 16; m <<= 1) ss += __shfl_xor(ss, m, 64);
        const float inv = osc / (sqrtf(ss) + 1e-6f);
        const int t = m0 + w * 32 + mt * 16 + quad * 4 + r;
        const float2 cs0 = ropeT[t * 32 + r16];
        const float2 cs1 = ropeT[t * 32 + 16 + r16];
        const float v0 = acc[mt][0][r] * inv, v1 = acc[mt][1][r] * inv;
        const float v2 = acc[mt][2][r] * inv, v3 = acc[mt][3][r] * inv;
        __bf16* dst = dstBase + (size_t)t * HD;
        dst[r16]      = (__bf16)(v0 * cs0.x - v2 * cs0.y);
        dst[16 + r16] = (__bf16)(v1 * cs1.x - v3 * cs1.y);
        dst[32 + r16] = (__bf16)(v2 * cs0.x + v0 * cs0.y);
        dst[48 + r16] = (__bf16)(v3 * cs1.x + v1 * cs1.y);
      }
    }
  } else {  // V: transpose to Vt[kvh][d][t] via reused LDS
    const int kvh = (n0 - 1280) >> 6;
    __syncthreads();
    __bf16* Vs = As;  // [64 d][stride 136]
#pragma unroll
    for (int mt = 0; mt < 2; ++mt)
#pragma unroll
      for (int nt = 0; nt < 4; ++nt)
#pragma unroll
        for (int r = 0; r < 4; ++r)
          Vs[(nt * 16 + r16) * 136 + w * 32 + mt * 16 + quad * 4 + r] = (__bf16)acc[mt][nt][r];
    __syncthreads();
    const int d = tid >> 2, tc = (tid & 3) * 32;
    __bf16* dst = Vt + ((size_t)kvh * HD + d) * T_SEQ + m0 + tc;
#pragma unroll
    for (int c2 = 0; c2 < 4; ++c2) {
      bf16x8 v = *(const bf16x8*)(Vs + d * 136 + tc + c2 * 8);
      *(bf16x8*)(dst + c2 * 8) = v;
    }
  }
}

// ---------------- proj GEMM: plain f32 epilogue ----------------
__global__ __launch_bounds__(256) void gemm_proj_kernel(const __bf16* __restrict__ Yb,
                                                        const __bf16* __restrict__ Wpb,
                                                        float* __restrict__ C) {
  __shared__ __align__(16) __bf16 As[2 * 8192];
  __shared__ __align__(16) __bf16 Bs[2 * 4096];
  f32x4 acc[2][4] = {};
  const int m0 = blockIdx.y * 128, n0 = blockIdx.x * 64;
  gemm_core(Yb, Wpb, C_DIM, m0, n0, As, Bs, acc);
  const int tid = threadIdx.x;
  const int w = tid >> 6, l = tid & 63, quad = l >> 4, r16 = l & 15;
#pragma unroll
  for (int mt = 0; mt < 2; ++mt) {
    const int mrow = m0 + w * 32 + mt * 16 + quad * 4;
    const int ncol = n0 + r16;
#pragma unroll
    for (int r = 0; r < 4; ++r) {
      size_t rowoff = (size_t)(mrow + r) * C_DIM;
      C[rowoff + ncol]      = acc[mt][0][r];
      C[rowoff + ncol + 16] = acc[mt][1][r];
      C[rowoff + ncol + 32] = acc[mt][2][r];
      C[rowoff + ncol + 48] = acc[mt][3][r];
    }
  }
}

// ---------------- MFMA sliding-window attention, pipelined chunk loop ----------------
// K-frags for chunk c+1 prefetched (double-buffered regs) while chunk c does exp+MFMA;
// V-frags loaded at chunk top, used at chunk bottom. Hides the serial per-chunk
// ~300-900 cyc load latency that dominated at 2 blocks/CU with cold caches.
__global__ __launch_bounds__(256, 2) void attn_mfma_kernel(const __bf16* __restrict__ Qb,
                                                           const __bf16* __restrict__ Kb,
                                                           const __bf16* __restrict__ Vt,
                                                           __bf16* __restrict__ Yb) {
  __shared__ __align__(16) __bf16 Pl[4][16][72];
  const int h = blockIdx.y, kvh = h >> 2;
  const int t0 = blockIdx.x * 64;
  const int tid = threadIdx.x;
  const int w = tid >> 6, l = tid & 63;
  const int quad = l >> 4, r16 = l & 15;
  const __bf16* qptr = Qb + ((size_t)h * T_SEQ + t0 + w * 16 + r16) * HD + quad * 8;
  bf16x8 aq0 = *(const bf16x8*)(qptr);
  bf16x8 aq1 = *(const bf16x8*)(qptr + 32);
  const int j0 = max(0, t0 - WIN);
  const int nch = (t0 + 64 - j0) >> 6;
  const __bf16* kbase = Kb + (size_t)kvh * T_SEQ * HD;
  const __bf16* vbase = Vt + (size_t)kvh * HD * T_SEQ;
  const int tq_base = t0 + w * 16 + quad * 4;
  f32x4 oacc[4] = {};
  float lsum[4] = {0.f, 0.f, 0.f, 0.f};
  bf16x8 kf[2][8];
#define LOADK(c, s)                                                                  \
  {                                                                                  \
    const int key0_ = j0 + ((c) << 6);                                               \
    _Pragma("unroll") for (int nt = 0; nt < 4; ++nt) {                               \
      const __bf16* kr = kbase + (size_t)(key0_ + nt * 16 + r16) * HD + quad * 8;    \
      kf[s][nt * 2]     = *(const bf16x8*)kr;                                        \
      kf[s][nt * 2 + 1] = *(const bf16x8*)(kr + 32);                                 \
    }                                                                                \
  }
  LOADK(0, 0);
  int cur = 0;
  for (int c = 0; c < nch; ++c) {
    const int key0 = j0 + (c << 6);
    if (c + 1 < nch) LOADK(c + 1, cur ^ 1);
    bf16x8 vf[8];
#pragma unroll
    for (int nt = 0; nt < 4; ++nt) {
      const __bf16* vr = vbase + (size_t)(nt * 16 + r16) * T_SEQ + key0 + quad * 8;
      vf[nt * 2]     = *(const bf16x8*)vr;
      vf[nt * 2 + 1] = *(const bf16x8*)(vr + 32);
    }
    f32x4 s[4] = {};
#pragma unroll
    for (int nt = 0; nt < 4; ++nt) {
      s[nt] = MFMA16(aq0, kf[cur][nt * 2], s[nt]);
      s[nt] = MFMA16(aq1, kf[cur][nt * 2 + 1], s[nt]);
    }
#pragma unroll
    for (int nt = 0; nt < 4; ++nt) {
      const int key = key0 + nt * 16 + r16;
#pragma unroll
      for (int r = 0; r < 4; ++r) {
        const int tq = tq_base + r;
        bool valid = (key <= tq) && (key > tq - WIN);
        float p = valid ? __expf(s[nt][r]) : 0.0f;
        lsum[r] += p;
        Pl[w][quad * 4 + r][nt * 16 + r16] = (__bf16)p;
      }
    }
    bf16x8 ap0 = *(const bf16x8*)(&Pl[w][r16][quad * 8]);
    bf16x8 ap1 = *(const bf16x8*)(&Pl[w][r16][32 + quad * 8]);
#pragma unroll
    for (int nt = 0; nt < 4; ++nt) {
      oacc[nt] = MFMA16(ap0, vf[nt * 2], oacc[nt]);
      oacc[nt] = MFMA16(ap1, vf[nt * 2 + 1], oacc[nt]);
    }
    cur ^= 1;
  }
#pragma unroll
  for (int r = 0; r < 4; ++r) {
#pragma unroll
    for (int m = 1; m < 16; m <<= 1) lsum[r] += __shfl_xor(lsum[r], m, 64);
    lsum[r] = 1.0f / lsum[r];
  }
#pragma unroll
  for (int r = 0; r < 4; ++r) {
    size_t row = (size_t)(tq_base + r);
#pragma unroll
    for (int nt = 0; nt < 4; ++nt) {
      Yb[row * C_DIM + h * HD + nt * 16 + r16] = (__bf16)(oacc[nt][r] * lsum[r]);
    }
  }
}

extern "C" void kernel_launch(void* const* d_in, const int* in_sizes, int n_in,
                              void* d_out, int out_size, void* d_ws, size_t ws_size,
                              hipStream_t stream) {
  const float* x     = (const float*)d_in[0];
  const float* Wq    = (const float*)d_in[1];
  const float* Wkv   = (const float*)d_in[2];
  const float* Wproj = (const float*)d_in[3];
  float* out = (float*)d_out;

  __bf16* xb    = (__bf16*)d_ws;                         // [2048][1024]
  __bf16* Wqkvb = xb + (size_t)T_SEQ * C_DIM;            // [1536][1024]
  __bf16* Wpb   = Wqkvb + (size_t)1536 * C_DIM;          // [1024][1024]
  __bf16* Qb    = Wpb + (size_t)C_DIM * C_DIM;           // [16][2048][64]
  __bf16* Kb    = Qb + (size_t)NH * T_SEQ * HD;          // [4][2048][64]
  __bf16* Vt    = Kb + (size_t)NKV * T_SEQ * HD;         // [4][64][2048]
  __bf16* Yb    = Vt + (size_t)NKV * HD * T_SEQ;         // [2048][1024]
  float2* ropeT = (float2*)(Yb + (size_t)T_SEQ * C_DIM); // [2048][32]

  prep_kernel<<<4864, 256, 0, stream>>>(x, Wq, Wkv, Wproj, xb, Wqkvb, Wpb, ropeT);
  gemm_qkv_kernel<<<dim3(24, 16), 256, 0, stream>>>(xb, Wqkvb, ropeT, Qb, Kb, Vt);
  attn_mfma_kernel<<<dim3(T_SEQ / 64, NH), 256, 0, stream>>>(Qb, Kb, Vt, Yb);
  gemm_proj_kernel<<<dim3(16, 16), 256, 0, stream>>>(Yb, Wpb, out);
}

// Round 7
// 140.662 us; speedup vs baseline: 1.5618x; 1.5618x over previous
//
#include <hip/hip_runtime.h>

#define T_SEQ 2048
#define C_DIM 1024
#define NH    16
#define NKV   4
#define HD    64
#define WIN   512

typedef __bf16 bf16x8 __attribute__((ext_vector_type(8)));
typedef __bf16 bf16x4 __attribute__((ext_vector_type(4)));
typedef float f32x4 __attribute__((ext_vector_type(4)));

#define MFMA16(a, b, c) __builtin_amdgcn_mfma_f32_16x16x32_bf16(a, b, c, 0, 0, 0)

// ---------------- prep: fused f32->bf16 casts + RoPE table ----------------
__global__ __launch_bounds__(256) void prep_kernel(const float* __restrict__ x,
                                                   const float* __restrict__ Wq,
                                                   const float* __restrict__ Wkv,
                                                   const float* __restrict__ Wp,
                                                   __bf16* __restrict__ xb,
                                                   __bf16* __restrict__ Wqkvb,
                                                   __bf16* __restrict__ Wpb,
                                                   float2* __restrict__ ropeT) {
  int b = blockIdx.x;
  if (b >= 4608) {
    int idx = (b - 4608) * 256 + threadIdx.x;  // < 65536
    int t = idx >> 5, i = idx & 31;
    float theta = exp2f(-(float)i * (13.287712379549449f / 32.0f));
    float s, c;
    sincosf((float)t * theta, &s, &c);
    ropeT[idx] = make_float2(c, s);
    return;
  }
  const float* src;
  __bf16* dst;
  int off;
  if (b < 2048)      { src = x;   dst = xb;                off = b; }
  else if (b < 3072) { src = Wq;  dst = Wqkvb;             off = b - 2048; }
  else if (b < 3584) { src = Wkv; dst = Wqkvb + (1 << 20); off = b - 3072; }
  else               { src = Wp;  dst = Wpb;               off = b - 3584; }
  int i = off * 1024 + threadIdx.x * 4;
  float4 v = *(const float4*)(src + i);
  bf16x4 o;
  o[0] = (__bf16)v.x; o[1] = (__bf16)v.y; o[2] = (__bf16)v.z; o[3] = (__bf16)v.w;
  *(bf16x4*)(dst + i) = o;
}

// ---------------- GEMM core: 128x64 tile, BK=64, depth-1 VGPR prefetch + LDS dbuf ----
// PROVEN in R5 (146 us total). R6's depth-2 variant spilled (65 MB scratch writes) --
// the 12 uint4 staging regs exceeded the budget. Keep depth-1 + sched_barrier.
__device__ __forceinline__ void gemm_core(const __bf16* __restrict__ A,
                                          const __bf16* __restrict__ B,
                                          int K, int m0, int n0,
                                          __bf16* AsB, __bf16* BsB,
                                          f32x4 (&acc)[2][4]) {
  const int tid = threadIdx.x;
  const int w = tid >> 6, l = tid & 63;
  const int quad = l >> 4, r16 = l & 15;
  const int arow = tid >> 1;
  const int brow = tid >> 2;
  const __bf16* gA = A + (size_t)(m0 + arow) * K + (tid & 1) * 32;
  const __bf16* gB = B + (size_t)(n0 + brow) * K + (tid & 3) * 16;
  int wA[4], wB[2];
#pragma unroll
  for (int q = 0; q < 4; ++q) wA[q] = arow * 64 + ((((tid & 1) * 4 + q) ^ (arow & 7)) * 8);
#pragma unroll
  for (int q = 0; q < 2; ++q) wB[q] = brow * 64 + ((((tid & 3) * 2 + q) ^ (brow & 7)) * 8);
  int rA[2][2], rB[4][2];
#pragma unroll
  for (int mt = 0; mt < 2; ++mt)
#pragma unroll
    for (int ks = 0; ks < 2; ++ks) {
      int row = w * 32 + mt * 16 + r16;
      rA[mt][ks] = row * 64 + (((ks * 4 + quad) ^ (row & 7)) * 8);
    }
#pragma unroll
  for (int nt = 0; nt < 4; ++nt)
#pragma unroll
    for (int ks = 0; ks < 2; ++ks) {
      int row = nt * 16 + r16;
      rB[nt][ks] = row * 64 + (((ks * 4 + quad) ^ (row & 7)) * 8);
    }
  const int nIter = K >> 6;
  uint4 pa[4], pb[2];
  {
    const uint4* a = (const uint4*)gA;
    pa[0] = a[0]; pa[1] = a[1]; pa[2] = a[2]; pa[3] = a[3];
    const uint4* b = (const uint4*)gB;
    pb[0] = b[0]; pb[1] = b[1];
  }
#pragma unroll
  for (int q = 0; q < 4; ++q) *(uint4*)(AsB + wA[q]) = pa[q];
#pragma unroll
  for (int q = 0; q < 2; ++q) *(uint4*)(BsB + wB[q]) = pb[q];
  __syncthreads();
  int cur = 0;
  for (int it = 0; it < nIter; ++it) {
    if (it + 1 < nIter) {
      const uint4* a = (const uint4*)(gA + ((it + 1) << 6));
      pa[0] = a[0]; pa[1] = a[1]; pa[2] = a[2]; pa[3] = a[3];
      const uint4* b = (const uint4*)(gB + ((it + 1) << 6));
      pb[0] = b[0]; pb[1] = b[1];
    }
    const __bf16* Asc = AsB + cur * 8192;
    const __bf16* Bsc = BsB + cur * 4096;
#pragma unroll
    for (int ks = 0; ks < 2; ++ks) {
      bf16x8 a0 = *(const bf16x8*)(Asc + rA[0][ks]);
      bf16x8 a1 = *(const bf16x8*)(Asc + rA[1][ks]);
      bf16x8 b0 = *(const bf16x8*)(Bsc + rB[0][ks]);
      bf16x8 b1 = *(const bf16x8*)(Bsc + rB[1][ks]);
      bf16x8 b2 = *(const bf16x8*)(Bsc + rB[2][ks]);
      bf16x8 b3 = *(const bf16x8*)(Bsc + rB[3][ks]);
      acc[0][0] = MFMA16(a0, b0, acc[0][0]);
      acc[0][1] = MFMA16(a0, b1, acc[0][1]);
      acc[0][2] = MFMA16(a0, b2, acc[0][2]);
      acc[0][3] = MFMA16(a0, b3, acc[0][3]);
      acc[1][0] = MFMA16(a1, b0, acc[1][0]);
      acc[1][1] = MFMA16(a1, b1, acc[1][1]);
      acc[1][2] = MFMA16(a1, b2, acc[1][2]);
      acc[1][3] = MFMA16(a1, b3, acc[1][3]);
    }
    if (it + 1 < nIter) {
      __builtin_amdgcn_sched_barrier(0);
      __bf16* Asn = AsB + (cur ^ 1) * 8192;
      __bf16* Bsn = BsB + (cur ^ 1) * 4096;
#pragma unroll
      for (int q = 0; q < 4; ++q) *(uint4*)(Asn + wA[q]) = pa[q];
#pragma unroll
      for (int q = 0; q < 2; ++q) *(uint4*)(BsB + (cur ^ 1) * 4096 + wB[q]) = pb[q];
      (void)Asn;
      __syncthreads();
      cur ^= 1;
    }
  }
}

// ---------------- QKV GEMM with fused norm+RoPE (Q,K) and V-transpose epilogue ----------
__global__ __launch_bounds__(256) void gemm_qkv_kernel(const __bf16* __restrict__ xb,
                                                       const __bf16* __restrict__ Wqkvb,
                                                       const float2* __restrict__ ropeT,
                                                       __bf16* __restrict__ Qb,
                                                       __bf16* __restrict__ Kb,
                                                       __bf16* __restrict__ Vt) {
  __shared__ __align__(16) __bf16 As[2 * 8192];
  __shared__ __align__(16) __bf16 Bs[2 * 4096];
  f32x4 acc[2][4] = {};
  const int m0 = blockIdx.y * 128, n0 = blockIdx.x * 64;
  gemm_core(xb, Wqkvb, C_DIM, m0, n0, As, Bs, acc);
  const int tid = threadIdx.x;
  const int w = tid >> 6, l = tid & 63, quad = l >> 4, r16 = l & 15;
  if (n0 < 1280) {  // Q or K: L2-norm + RoPE
    const bool isQ = n0 < 1024;
    const int head = isQ ? (n0 >> 6) : ((n0 - 1024) >> 6);
    __bf16* dstBase = (isQ ? Qb : Kb) + (size_t)head * T_SEQ * HD;
    const float osc = isQ ? 0.125f : 1.0f;
#pragma unroll
    for (int mt = 0; mt < 2; ++mt) {
#pragma unroll
      for (int r = 0; r < 4; ++r) {
        float ss = acc[mt][0][r] * acc[mt][0][r] + acc[mt][1][r] * acc[mt][1][r] +
                   acc[mt][2][r] * acc[mt][2][r] + acc[mt][3][r] * acc[mt][3][r];
#pragma unroll
        for (int m = 1; m < 16; m <<= 1) ss += __shfl_xor(ss, m, 64);
        const float inv = osc / (sqrtf(ss) + 1e-6f);
        const int t = m0 + w * 32 + mt * 16 + quad * 4 + r;
        const float2 cs0 = ropeT[t * 32 + r16];
        const float2 cs1 = ropeT[t * 32 + 16 + r16];
        const float v0 = acc[mt][0][r] * inv, v1 = acc[mt][1][r] * inv;
        const float v2 = acc[mt][2][r] * inv, v3 = acc[mt][3][r] * inv;
        __bf16* dst = dstBase + (size_t)t * HD;
        dst[r16]      = (__bf16)(v0 * cs0.x - v2 * cs0.y);
        dst[16 + r16] = (__bf16)(v1 * cs1.x - v3 * cs1.y);
        dst[32 + r16] = (__bf16)(v2 * cs0.x + v0 * cs0.y);
        dst[48 + r16] = (__bf16)(v3 * cs1.x + v1 * cs1.y);
      }
    }
  } else {  // V: transpose to Vt[kvh][d][t] via reused LDS
    const int kvh = (n0 - 1280) >> 6;
    __syncthreads();
    __bf16* Vs = As;  // [64 d][stride 136]
#pragma unroll
    for (int mt = 0; mt < 2; ++mt)
#pragma unroll
      for (int nt = 0; nt < 4; ++nt)
#pragma unroll
        for (int r = 0; r < 4; ++r)
          Vs[(nt * 16 + r16) * 136 + w * 32 + mt * 16 + quad * 4 + r] = (__bf16)acc[mt][nt][r];
    __syncthreads();
    const int d = tid >> 2, tc = (tid & 3) * 32;
    __bf16* dst = Vt + ((size_t)kvh * HD + d) * T_SEQ + m0 + tc;
#pragma unroll
    for (int c2 = 0; c2 < 4; ++c2) {
      bf16x8 v = *(const bf16x8*)(Vs + d * 136 + tc + c2 * 8);
      *(bf16x8*)(dst + c2 * 8) = v;
    }
  }
}

// ---------------- proj GEMM: plain f32 epilogue ----------------
__global__ __launch_bounds__(256) void gemm_proj_kernel(const __bf16* __restrict__ Yb,
                                                        const __bf16* __restrict__ Wpb,
                                                        float* __restrict__ C) {
  __shared__ __align__(16) __bf16 As[2 * 8192];
  __shared__ __align__(16) __bf16 Bs[2 * 4096];
  f32x4 acc[2][4] = {};
  const int m0 = blockIdx.y * 128, n0 = blockIdx.x * 64;
  gemm_core(Yb, Wpb, C_DIM, m0, n0, As, Bs, acc);
  const int tid = threadIdx.x;
  const int w = tid >> 6, l = tid & 63, quad = l >> 4, r16 = l & 15;
#pragma unroll
  for (int mt = 0; mt < 2; ++mt) {
    const int mrow = m0 + w * 32 + mt * 16 + quad * 4;
    const int ncol = n0 + r16;
#pragma unroll
    for (int r = 0; r < 4; ++r) {
      size_t rowoff = (size_t)(mrow + r) * C_DIM;
      C[rowoff + ncol]      = acc[mt][0][r];
      C[rowoff + ncol + 16] = acc[mt][1][r];
      C[rowoff + ncol + 32] = acc[mt][2][r];
      C[rowoff + ncol + 48] = acc[mt][3][r];
    }
  }
}

// ---------------- MFMA sliding-window attention, split-key blocks ----------------
// grid (T/32, NH), block 256 = 4 waves. Q-tile = 32 queries. Wave w: sub=w&1 picks the
// 16-query subtile, half=w>>1 picks the key-chunk half. 1024 blocks = 4 blocks/CU =
// 16 waves/CU (R6's 512-block version capped at 2 blocks/CU, Occ 17%, latency-bound).
// Partial (O, lsum) from the half=1 waves combined through LDS -- valid without
// online-max because |s| <= 0.125 (unit q,k, scale folded) so exp is bounded.
// Chunk body = R3 direct-load form (NO register prefetch -- that spilled: R6 showed
// 133 MB scratch writes). keyStart aligned down to 64 => loads stay in [0,T).
__global__ __launch_bounds__(256) void attn_mfma_kernel(const __bf16* __restrict__ Qb,
                                                        const __bf16* __restrict__ Kb,
                                                        const __bf16* __restrict__ Vt,
                                                        __bf16* __restrict__ Yb) {
  __shared__ __align__(16) __bf16 Pl[4][16][72];
  __shared__ __align__(16) float Oc[2][16][68];  // stride 68: quad rows land 2-way (free)
  __shared__ float Ls[2][16];
  const int h = blockIdx.y, kvh = h >> 2;
  const int t0 = blockIdx.x * 32;
  const int tid = threadIdx.x;
  const int w = tid >> 6, l = tid & 63;
  const int quad = l >> 4, r16 = l & 15;
  const int sub = w & 1, half = w >> 1;
  const __bf16* qptr = Qb + ((size_t)h * T_SEQ + t0 + sub * 16 + r16) * HD + quad * 8;
  bf16x8 aq0 = *(const bf16x8*)(qptr);
  bf16x8 aq1 = *(const bf16x8*)(qptr + 32);
  const int keyStart = max(0, t0 - (WIN - 1)) & ~63;
  const int keyEnd = (t0 + 32 + 63) & ~63;
  const int nch = (keyEnd - keyStart) >> 6;   // <= 9
  const int nch2 = (nch + 1) >> 1;
  const int cbeg = half ? nch2 : 0;
  const int cend = half ? nch : nch2;
  const __bf16* kbase = Kb + (size_t)kvh * T_SEQ * HD;
  const __bf16* vbase = Vt + (size_t)kvh * HD * T_SEQ;
  const int tq_base = t0 + sub * 16 + quad * 4;
  f32x4 oacc[4] = {};
  float lsum[4] = {0.f, 0.f, 0.f, 0.f};
  for (int c = cbeg; c < cend; ++c) {
    const int key0 = keyStart + (c << 6);
    f32x4 s[4] = {};
#pragma unroll
    for (int nt = 0; nt < 4; ++nt) {
      const __bf16* kr = kbase + (size_t)(key0 + nt * 16 + r16) * HD + quad * 8;
      bf16x8 bk0 = *(const bf16x8*)kr;
      bf16x8 bk1 = *(const bf16x8*)(kr + 32);
      s[nt] = MFMA16(aq0, bk0, s[nt]);
      s[nt] = MFMA16(aq1, bk1, s[nt]);
    }
#pragma unroll
    for (int nt = 0; nt < 4; ++nt) {
      const int key = key0 + nt * 16 + r16;
#pragma unroll
      for (int r = 0; r < 4; ++r) {
        const int tq = tq_base + r;
        bool valid = (key <= tq) && (key > tq - WIN);
        float p = valid ? __expf(s[nt][r]) : 0.0f;
        lsum[r] += p;
        Pl[w][quad * 4 + r][nt * 16 + r16] = (__bf16)p;
      }
    }
    bf16x8 ap0 = *(const bf16x8*)(&Pl[w][r16][quad * 8]);
    bf16x8 ap1 = *(const bf16x8*)(&Pl[w][r16][32 + quad * 8]);
#pragma unroll
    for (int nt = 0; nt < 4; ++nt) {
      const __bf16* vr = vbase + (size_t)(nt * 16 + r16) * T_SEQ + key0 + quad * 8;
      bf16x8 bv0 = *(const bf16x8*)vr;
      bf16x8 bv1 = *(const bf16x8*)(vr + 32);
      oacc[nt] = MFMA16(ap0, bv0, oacc[nt]);
      oacc[nt] = MFMA16(ap1, bv1, oacc[nt]);
    }
  }
  // row-sum across the 16 key-columns held per quad group
#pragma unroll
  for (int r = 0; r < 4; ++r) {
#pragma unroll
    for (int m = 1; m < 16; m <<= 1) lsum[r] += __shfl_xor(lsum[r], m, 64);
  }
  if (half == 1) {  // publish partials
#pragma unroll
    for (int nt = 0; nt < 4; ++nt)
#pragma unroll
      for (int r = 0; r < 4; ++r)
        Oc[sub][quad * 4 + r][nt * 16 + r16] = oacc[nt][r];
    if (r16 == 0) {
#pragma unroll
      for (int r = 0; r < 4; ++r) Ls[sub][quad * 4 + r] = lsum[r];
    }
  }
  __syncthreads();
  if (half == 0) {  // combine + normalize + store
#pragma unroll
    for (int r = 0; r < 4; ++r) {
      const float inv = 1.0f / (lsum[r] + Ls[sub][quad * 4 + r]);
      const size_t row = (size_t)(tq_base + r);
#pragma unroll
      for (int nt = 0; nt < 4; ++nt) {
        float o = oacc[nt][r] + Oc[sub][quad * 4 + r][nt * 16 + r16];
        Yb[row * C_DIM + h * HD + nt * 16 + r16] = (__bf16)(o * inv);
      }
    }
  }
}

extern "C" void kernel_launch(void* const* d_in, const int* in_sizes, int n_in,
                              void* d_out, int out_size, void* d_ws, size_t ws_size,
                              hipStream_t stream) {
  const float* x     = (const float*)d_in[0];
  const float* Wq    = (const float*)d_in[1];
  const float* Wkv   = (const float*)d_in[2];
  const float* Wproj = (const float*)d_in[3];
  float* out = (float*)d_out;

  __bf16* xb    = (__bf16*)d_ws;                         // [2048][1024]
  __bf16* Wqkvb = xb + (size_t)T_SEQ * C_DIM;            // [1536][1024]
  __bf16* Wpb   = Wqkvb + (size_t)1536 * C_DIM;          // [1024][1024]
  __bf16* Qb    = Wpb + (size_t)C_DIM * C_DIM;           // [16][2048][64]
  __bf16* Kb    = Qb + (size_t)NH * T_SEQ * HD;          // [4][2048][64]
  __bf16* Vt    = Kb + (size_t)NKV * T_SEQ * HD;         // [4][64][2048]
  __bf16* Yb    = Vt + (size_t)NKV * HD * T_SEQ;         // [2048][1024]
  float2* ropeT = (float2*)(Yb + (size_t)T_SEQ * C_DIM); // [2048][32]

  prep_kernel<<<4864, 256, 0, stream>>>(x, Wq, Wkv, Wproj, xb, Wqkvb, Wpb, ropeT);
  gemm_qkv_kernel<<<dim3(24, 16), 256, 0, stream>>>(xb, Wqkvb, ropeT, Qb, Kb, Vt);
  attn_mfma_kernel<<<dim3(T_SEQ / 32, NH), 256, 0, stream>>>(Qb, Kb, Vt, Yb);
  gemm_proj_kernel<<<dim3(16, 16), 256, 0, stream>>>(Yb, Wpb, out);
}